// Round 1
// baseline (604.868 us; speedup 1.0000x reference)
//
#include <hip/hip_runtime.h>
#include <cstddef>
#include <cstdint>

typedef _Float16 f16x8 __attribute__((ext_vector_type(8)));
typedef _Float16 f16x4 __attribute__((ext_vector_type(4)));
typedef float f32x4 __attribute__((ext_vector_type(4)));

static constexpr int BATCH = 8;
static constexpr int TQ = 2048;
static constexpr int TK = 2048;
static constexpr int DIM = 1024;
static constexpr size_t CTX_ELEMS = (size_t)BATCH * TQ * DIM;  // 16,777,216

static constexpr int BM = 128, BN = 128, BK = 32;
static constexpr int LDSS = 40;  // halves per LDS row: 32 data + 8 pad (80 B rows, 16B aligned)

__device__ __forceinline__ f16x8 cvt8(float4 a, float4 b) {
  f16x8 h;
  h[0] = (_Float16)a.x; h[1] = (_Float16)a.y; h[2] = (_Float16)a.z; h[3] = (_Float16)a.w;
  h[4] = (_Float16)b.x; h[5] = (_Float16)b.y; h[6] = (_Float16)b.z; h[7] = (_Float16)b.w;
  return h;
}

// ---------------------------------------------------------------------------
// Kernel 1: S[b,q,k] = dot(dec[b,q,:], enc[b,k,:])   (NT GEMM, fp16 MFMA)
// Writes raw fp32 scores into the attention region of d_out.
// ---------------------------------------------------------------------------
__global__ __launch_bounds__(256) void score_kernel(
    const float* __restrict__ dec, const float* __restrict__ enc,
    float* __restrict__ S) {
  __shared__ _Float16 sA[BM * LDSS];
  __shared__ _Float16 sB[BN * LDSS];

  const int nt = blockIdx.x, mt = blockIdx.y, b = blockIdx.z;
  const int t = threadIdx.x;
  const int lane = t & 63, wave = t >> 6;
  const int wm = wave >> 1, wn = wave & 1;
  const int tm = lane & 15, quad = lane >> 4;

  const float* Abase = dec + ((size_t)b * TQ + mt * BM) * DIM;
  const float* Bbase = enc + ((size_t)b * TK + nt * BN) * DIM;

  f32x4 acc[4][4] = {};

  const int r = t >> 2;          // 0..63  (staging row, and row+64)
  const int c8 = (t & 3) * 8;    // 0,8,16,24

  for (int k0 = 0; k0 < DIM; k0 += BK) {
    float4 a0 = *(const float4*)(Abase + (size_t)r * DIM + k0 + c8);
    float4 a1 = *(const float4*)(Abase + (size_t)r * DIM + k0 + c8 + 4);
    float4 a2 = *(const float4*)(Abase + (size_t)(r + 64) * DIM + k0 + c8);
    float4 a3 = *(const float4*)(Abase + (size_t)(r + 64) * DIM + k0 + c8 + 4);
    float4 b0 = *(const float4*)(Bbase + (size_t)r * DIM + k0 + c8);
    float4 b1 = *(const float4*)(Bbase + (size_t)r * DIM + k0 + c8 + 4);
    float4 b2 = *(const float4*)(Bbase + (size_t)(r + 64) * DIM + k0 + c8);
    float4 b3 = *(const float4*)(Bbase + (size_t)(r + 64) * DIM + k0 + c8 + 4);

    __syncthreads();  // previous iteration's LDS reads done
    *(f16x8*)&sA[r * LDSS + c8]        = cvt8(a0, a1);
    *(f16x8*)&sA[(r + 64) * LDSS + c8] = cvt8(a2, a3);
    *(f16x8*)&sB[r * LDSS + c8]        = cvt8(b0, b1);
    *(f16x8*)&sB[(r + 64) * LDSS + c8] = cvt8(b2, b3);
    __syncthreads();

    f16x8 aF[4], bF[4];
#pragma unroll
    for (int i = 0; i < 4; i++)
      aF[i] = *(const f16x8*)&sA[(wm * 64 + i * 16 + tm) * LDSS + quad * 8];
#pragma unroll
    for (int j = 0; j < 4; j++)
      bF[j] = *(const f16x8*)&sB[(wn * 64 + j * 16 + tm) * LDSS + quad * 8];

#pragma unroll
    for (int i = 0; i < 4; i++)
#pragma unroll
      for (int j = 0; j < 4; j++)
        acc[i][j] = __builtin_amdgcn_mfma_f32_16x16x32_f16(aF[i], bF[j], acc[i][j], 0, 0, 0);
  }

  // Epilogue: C/D layout col = lane&15, row = quad*4 + reg
#pragma unroll
  for (int i = 0; i < 4; i++) {
#pragma unroll
    for (int rr = 0; rr < 4; rr++) {
      size_t rowoff = ((size_t)b * TQ + mt * BM + wm * 64 + i * 16 + quad * 4 + rr) * (size_t)TK;
#pragma unroll
      for (int j = 0; j < 4; j++)
        S[rowoff + nt * BN + wn * 64 + j * 16 + tm] = acc[i][j][rr];
    }
  }
}

// ---------------------------------------------------------------------------
// Kernel 2: in-place masked row softmax over S[b*TQ+q, :]  (one block per row)
// Matches ref: score + (1-mask)*(-1e9), softmax over k.
// ---------------------------------------------------------------------------
__global__ __launch_bounds__(256) void softmax_kernel(
    float* __restrict__ S, const int* __restrict__ mask) {
  const int row = blockIdx.x;
  const int b = row >> 11;  // row / TQ
  float* srow = S + (size_t)row * TK;
  const int* mrow = mask + (size_t)b * TK;
  const int t = threadIdx.x;

  float4 s0 = *(const float4*)(srow + t * 8);
  float4 s1 = *(const float4*)(srow + t * 8 + 4);
  int4 m0 = *(const int4*)(mrow + t * 8);
  int4 m1 = *(const int4*)(mrow + t * 8 + 4);

  float v[8] = {s0.x, s0.y, s0.z, s0.w, s1.x, s1.y, s1.z, s1.w};
  const int mm[8] = {m0.x, m0.y, m0.z, m0.w, m1.x, m1.y, m1.z, m1.w};
#pragma unroll
  for (int i = 0; i < 8; i++)
    if (!mm[i]) v[i] += -1e9f;

  float mx = v[0];
#pragma unroll
  for (int i = 1; i < 8; i++) mx = fmaxf(mx, v[i]);
#pragma unroll
  for (int off = 32; off > 0; off >>= 1) mx = fmaxf(mx, __shfl_down(mx, off));

  __shared__ float redm[4];
  __shared__ float reds[4];
  if ((t & 63) == 0) redm[t >> 6] = mx;
  __syncthreads();
  mx = fmaxf(fmaxf(redm[0], redm[1]), fmaxf(redm[2], redm[3]));

  float e[8];
  float lsum = 0.f;
#pragma unroll
  for (int i = 0; i < 8; i++) {
    e[i] = __expf(v[i] - mx);
    lsum += e[i];
  }
#pragma unroll
  for (int off = 32; off > 0; off >>= 1) lsum += __shfl_down(lsum, off);
  if ((t & 63) == 0) reds[t >> 6] = lsum;
  __syncthreads();
  const float inv = 1.0f / (reds[0] + reds[1] + reds[2] + reds[3]);

  float4 o0 = {e[0] * inv, e[1] * inv, e[2] * inv, e[3] * inv};
  float4 o1 = {e[4] * inv, e[5] * inv, e[6] * inv, e[7] * inv};
  *(float4*)(srow + t * 8) = o0;
  *(float4*)(srow + t * 8 + 4) = o1;
}

// ---------------------------------------------------------------------------
// Kernel 3: ctx[b,q,d] = sum_k W[b,q,k] * enc[b,k,d]   (NN GEMM, fp16 MFMA)
// A (W) staged like kernel 1; B (enc) staged TRANSPOSED into LDS [n][k].
// ---------------------------------------------------------------------------
__global__ __launch_bounds__(256) void ctx_kernel(
    const float* __restrict__ W, const float* __restrict__ enc,
    float* __restrict__ C) {
  __shared__ _Float16 sA[BM * LDSS];
  __shared__ _Float16 sB[BN * LDSS];

  const int nt = blockIdx.x;  // 0..7  over DIM
  const int mt = blockIdx.y;  // 0..15 over TQ
  const int b = blockIdx.z;
  const int t = threadIdx.x;
  const int lane = t & 63, wave = t >> 6;
  const int wm = wave >> 1, wn = wave & 1;
  const int tm = lane & 15, quad = lane >> 4;

  const float* Abase = W + ((size_t)b * TQ + mt * BM) * TK;
  const float* Ebase = enc + (size_t)b * TK * DIM + nt * BN;

  f32x4 acc[4][4] = {};

  const int r = t >> 2;
  const int c8 = (t & 3) * 8;
  const int kkB = (t & 7) * 4;   // 0..28
  const int nnB = (t >> 3) * 4;  // 0..124

  for (int k0 = 0; k0 < TK; k0 += BK) {
    float4 a0 = *(const float4*)(Abase + (size_t)r * TK + k0 + c8);
    float4 a1 = *(const float4*)(Abase + (size_t)r * TK + k0 + c8 + 4);
    float4 a2 = *(const float4*)(Abase + (size_t)(r + 64) * TK + k0 + c8);
    float4 a3 = *(const float4*)(Abase + (size_t)(r + 64) * TK + k0 + c8 + 4);
    float4 f[4];
#pragma unroll
    for (int i = 0; i < 4; i++)
      f[i] = *(const float4*)(Ebase + (size_t)(k0 + kkB + i) * DIM + nnB);

    __syncthreads();
    *(f16x8*)&sA[r * LDSS + c8]        = cvt8(a0, a1);
    *(f16x8*)&sA[(r + 64) * LDSS + c8] = cvt8(a2, a3);
#pragma unroll
    for (int c = 0; c < 4; c++) {
      f16x4 h;
      h[0] = (_Float16)((&f[0].x)[c]);
      h[1] = (_Float16)((&f[1].x)[c]);
      h[2] = (_Float16)((&f[2].x)[c]);
      h[3] = (_Float16)((&f[3].x)[c]);
      *(f16x4*)&sB[(nnB + c) * LDSS + kkB] = h;
    }
    __syncthreads();

    f16x8 aF[4], bF[4];
#pragma unroll
    for (int i = 0; i < 4; i++)
      aF[i] = *(const f16x8*)&sA[(wm * 64 + i * 16 + tm) * LDSS + quad * 8];
#pragma unroll
    for (int j = 0; j < 4; j++)
      bF[j] = *(const f16x8*)&sB[(wn * 64 + j * 16 + tm) * LDSS + quad * 8];

#pragma unroll
    for (int i = 0; i < 4; i++)
#pragma unroll
      for (int j = 0; j < 4; j++)
        acc[i][j] = __builtin_amdgcn_mfma_f32_16x16x32_f16(aF[i], bF[j], acc[i][j], 0, 0, 0);
  }

#pragma unroll
  for (int i = 0; i < 4; i++) {
#pragma unroll
    for (int rr = 0; rr < 4; rr++) {
      size_t rowoff = ((size_t)b * TQ + mt * BM + wm * 64 + i * 16 + quad * 4 + rr) * (size_t)DIM;
#pragma unroll
      for (int j = 0; j < 4; j++)
        C[rowoff + nt * BN + wn * 64 + j * 16 + tm] = acc[i][j][rr];
    }
  }
}

// ---------------------------------------------------------------------------
extern "C" void kernel_launch(void* const* d_in, const int* in_sizes, int n_in,
                              void* d_out, int out_size, void* d_ws, size_t ws_size,
                              hipStream_t stream) {
  const float* dec = (const float*)d_in[0];
  const float* enc = (const float*)d_in[1];
  const int* mask = (const int*)d_in[2];

  float* ctx = (float*)d_out;               // [8, 2048, 1024]
  float* attn = (float*)d_out + CTX_ELEMS;  // [8, 2048, 2048]

  dim3 block(256);
  score_kernel<<<dim3(TK / BN, TQ / BM, BATCH), block, 0, stream>>>(dec, enc, attn);
  softmax_kernel<<<dim3(BATCH * TQ), block, 0, stream>>>(attn, mask);
  ctx_kernel<<<dim3(DIM / BN, TQ / BM, BATCH), block, 0, stream>>>(attn, enc, ctx);
}

// Round 2
// 593.946 us; speedup vs baseline: 1.0184x; 1.0184x over previous
//
#include <hip/hip_runtime.h>
#include <cstddef>
#include <cstdint>

typedef _Float16 f16x8 __attribute__((ext_vector_type(8)));
typedef _Float16 f16x4 __attribute__((ext_vector_type(4)));
typedef float f32x4 __attribute__((ext_vector_type(4)));

static constexpr int BATCH = 8;
static constexpr int TQ = 2048;
static constexpr int TK = 2048;
static constexpr int DIM = 1024;
static constexpr size_t CTX_ELEMS = (size_t)BATCH * TQ * DIM;   // 16,777,216
static constexpr size_t ATT_ELEMS = (size_t)BATCH * TQ * TK;    // 33,554,432

// ws layout (halves): dec16 | enc16 | encT16 | W16
static constexpr size_t WS_DEC = 0;
static constexpr size_t WS_ENC = WS_DEC + CTX_ELEMS;
static constexpr size_t WS_ENCT = WS_ENC + CTX_ELEMS;
static constexpr size_t WS_W = WS_ENCT + CTX_ELEMS;
static constexpr size_t WS_NEEDED_BYTES = (WS_W + ATT_ELEMS) * 2;  // 167.8 MB

__device__ __forceinline__ void async16(const void* g, const void* l) {
  __builtin_amdgcn_global_load_lds(
      (const __attribute__((address_space(1))) unsigned int*)g,
      (__attribute__((address_space(3))) unsigned int*)l, 16, 0, 0);
}

__device__ __forceinline__ f16x8 cvt8(float4 a, float4 b) {
  f16x8 h;
  h[0] = (_Float16)a.x; h[1] = (_Float16)a.y; h[2] = (_Float16)a.z; h[3] = (_Float16)a.w;
  h[4] = (_Float16)b.x; h[5] = (_Float16)b.y; h[6] = (_Float16)b.z; h[7] = (_Float16)b.w;
  return h;
}

// ===========================================================================
// FAST PATH (needs 168 MB ws)
// ===========================================================================

// fp32 -> fp16 elementwise: y selects dec (0) or enc (1).
__global__ __launch_bounds__(256) void convert_kernel(
    const float* __restrict__ dec, const float* __restrict__ enc,
    _Float16* __restrict__ dec16, _Float16* __restrict__ enc16) {
  const float* src = blockIdx.y ? enc : dec;
  _Float16* dst = blockIdx.y ? enc16 : dec16;
  size_t i = ((size_t)blockIdx.x * 256 + threadIdx.x) * 8;
  float4 a = *(const float4*)(src + i);
  float4 b = *(const float4*)(src + i + 4);
  *(f16x8*)(dst + i) = cvt8(a, b);
}

// enc fp32 [b][k][d] -> encT16 fp16 [b][d][k], 64x64 tiles via LDS.
__global__ __launch_bounds__(256) void transpose_kernel(
    const float* __restrict__ enc, _Float16* __restrict__ encT) {
  __shared__ _Float16 sT[64 * 72];
  const int k0 = blockIdx.x * 64, d0 = blockIdx.y * 64, b = blockIdx.z;
  const int t = threadIdx.x;
  const int krow = t >> 2;           // 0..63
  const int dcol = (t & 3) * 16;     // 0,16,32,48

  const float* src = enc + ((size_t)b * TK + k0 + krow) * DIM + d0 + dcol;
  float4 f0 = *(const float4*)(src);
  float4 f1 = *(const float4*)(src + 4);
  float4 f2 = *(const float4*)(src + 8);
  float4 f3 = *(const float4*)(src + 12);
  _Float16 h[16];
#pragma unroll
  for (int i = 0; i < 4; i++) {
    h[i]      = (_Float16)((&f0.x)[i]);
    h[i + 4]  = (_Float16)((&f1.x)[i]);
    h[i + 8]  = (_Float16)((&f2.x)[i]);
    h[i + 12] = (_Float16)((&f3.x)[i]);
  }
#pragma unroll
  for (int i = 0; i < 16; i++)
    sT[(dcol + i) * 72 + krow] = h[i];  // store transposed [d][k]
  __syncthreads();

  const int drow = t >> 2;
  const int kg = (t & 3) * 16;
  f16x8 v0 = *(const f16x8*)&sT[drow * 72 + kg];
  f16x8 v1 = *(const f16x8*)&sT[drow * 72 + kg + 8];
  _Float16* dst = encT + ((size_t)b * DIM + d0 + drow) * TK + k0 + kg;
  *(f16x8*)dst = v0;
  *(f16x8*)(dst + 8) = v1;
}

// m97-style NT GEMM: A[b][M][K], B[b][N][K] fp16 k-contiguous; C[b][M][N] fp32.
template <int M, int N, int K>
__global__ __launch_bounds__(256) void gemm_nt(
    const _Float16* __restrict__ A, const _Float16* __restrict__ B,
    float* __restrict__ C) {
  __shared__ _Float16 sA[128 * 32];
  __shared__ _Float16 sB[128 * 32];

  const int nt = blockIdx.x, mt = blockIdx.y, b = blockIdx.z;
  const int t = threadIdx.x;
  const int lane = t & 63, w = t >> 6;
  const int wm = w >> 1, wn = w & 1;
  const int tm = lane & 15, quad = lane >> 4;

  const _Float16* Ab = A + ((size_t)b * M + mt * 128) * K;
  const _Float16* Bb = B + ((size_t)b * N + nt * 128) * K;

  const int srow = lane >> 2;        // 0..15
  const int scol = (lane & 3) * 8;   // 0,8,16,24 halves

  f32x4 acc[4][4] = {};

  for (int k0 = 0; k0 < K; k0 += 32) {
    __syncthreads();  // previous iteration's LDS reads done
    // wave w stages rows [w*32, w*32+32) of both tiles; LDS dest wave-uniform.
    async16(Ab + (size_t)(w * 32 + srow) * K + k0 + scol, sA + (w * 32) * 32);
    async16(Ab + (size_t)(w * 32 + 16 + srow) * K + k0 + scol, sA + (w * 32 + 16) * 32);
    async16(Bb + (size_t)(w * 32 + srow) * K + k0 + scol, sB + (w * 32) * 32);
    async16(Bb + (size_t)(w * 32 + 16 + srow) * K + k0 + scol, sB + (w * 32 + 16) * 32);
    __syncthreads();  // staging drained (vmcnt) + all waves arrived

    f16x8 aF[4], bF[4];
#pragma unroll
    for (int i = 0; i < 4; i++)
      aF[i] = *(const f16x8*)&sA[(wm * 64 + i * 16 + tm) * 32 + quad * 8];
#pragma unroll
    for (int j = 0; j < 4; j++)
      bF[j] = *(const f16x8*)&sB[(wn * 64 + j * 16 + tm) * 32 + quad * 8];

#pragma unroll
    for (int i = 0; i < 4; i++)
#pragma unroll
      for (int j = 0; j < 4; j++)
        acc[i][j] = __builtin_amdgcn_mfma_f32_16x16x32_f16(aF[i], bF[j], acc[i][j], 0, 0, 0);
  }

  // C/D layout: col = lane&15, row = quad*4 + reg
#pragma unroll
  for (int i = 0; i < 4; i++) {
#pragma unroll
    for (int rr = 0; rr < 4; rr++) {
      size_t rowoff = ((size_t)b * M + mt * 128 + wm * 64 + i * 16 + quad * 4 + rr) * (size_t)N;
#pragma unroll
      for (int j = 0; j < 4; j++)
        C[rowoff + nt * 128 + wn * 64 + j * 16 + tm] = acc[i][j][rr];
    }
  }
}

// masked softmax in-place over S rows; optionally also emits fp16 copy.
__global__ __launch_bounds__(256) void softmax_kernel(
    float* __restrict__ S, const int* __restrict__ mask, _Float16* __restrict__ W16) {
  const int row = blockIdx.x;
  const int b = row >> 11;
  float* srow = S + (size_t)row * TK;
  const int* mrow = mask + (size_t)b * TK;
  const int t = threadIdx.x;

  float4 s0 = *(const float4*)(srow + t * 8);
  float4 s1 = *(const float4*)(srow + t * 8 + 4);
  int4 m0 = *(const int4*)(mrow + t * 8);
  int4 m1 = *(const int4*)(mrow + t * 8 + 4);

  float v[8] = {s0.x, s0.y, s0.z, s0.w, s1.x, s1.y, s1.z, s1.w};
  const int mm[8] = {m0.x, m0.y, m0.z, m0.w, m1.x, m1.y, m1.z, m1.w};
#pragma unroll
  for (int i = 0; i < 8; i++)
    if (!mm[i]) v[i] += -1e9f;

  float mx = v[0];
#pragma unroll
  for (int i = 1; i < 8; i++) mx = fmaxf(mx, v[i]);
#pragma unroll
  for (int off = 32; off > 0; off >>= 1) mx = fmaxf(mx, __shfl_down(mx, off));

  __shared__ float redm[4];
  __shared__ float reds[4];
  if ((t & 63) == 0) redm[t >> 6] = mx;
  __syncthreads();
  mx = fmaxf(fmaxf(redm[0], redm[1]), fmaxf(redm[2], redm[3]));

  float e[8];
  float lsum = 0.f;
#pragma unroll
  for (int i = 0; i < 8; i++) {
    e[i] = __expf(v[i] - mx);
    lsum += e[i];
  }
#pragma unroll
  for (int off = 32; off > 0; off >>= 1) lsum += __shfl_down(lsum, off);
  if ((t & 63) == 0) reds[t >> 6] = lsum;
  __syncthreads();
  const float inv = 1.0f / (reds[0] + reds[1] + reds[2] + reds[3]);

  float4 o0 = {e[0] * inv, e[1] * inv, e[2] * inv, e[3] * inv};
  float4 o1 = {e[4] * inv, e[5] * inv, e[6] * inv, e[7] * inv};
  *(float4*)(srow + t * 8) = o0;
  *(float4*)(srow + t * 8 + 4) = o1;
  if (W16) {
    f16x8 h;
    h[0] = (_Float16)o0.x; h[1] = (_Float16)o0.y; h[2] = (_Float16)o0.z; h[3] = (_Float16)o0.w;
    h[4] = (_Float16)o1.x; h[5] = (_Float16)o1.y; h[6] = (_Float16)o1.z; h[7] = (_Float16)o1.w;
    *(f16x8*)(W16 + (size_t)row * TK + t * 8) = h;
  }
}

// ===========================================================================
// FALLBACK PATH (round-1 kernels, used only if ws too small)
// ===========================================================================
static constexpr int BM = 128, BN = 128, BK = 32;
static constexpr int LDSS = 40;

__global__ __launch_bounds__(256) void score_kernel_fb(
    const float* __restrict__ dec, const float* __restrict__ enc,
    float* __restrict__ S) {
  __shared__ _Float16 sA[BM * LDSS];
  __shared__ _Float16 sB[BN * LDSS];
  const int nt = blockIdx.x, mt = blockIdx.y, b = blockIdx.z;
  const int t = threadIdx.x;
  const int lane = t & 63, wave = t >> 6;
  const int wm = wave >> 1, wn = wave & 1;
  const int tm = lane & 15, quad = lane >> 4;
  const float* Abase = dec + ((size_t)b * TQ + mt * BM) * DIM;
  const float* Bbase = enc + ((size_t)b * TK + nt * BN) * DIM;
  f32x4 acc[4][4] = {};
  const int r = t >> 2;
  const int c8 = (t & 3) * 8;
  for (int k0 = 0; k0 < DIM; k0 += BK) {
    float4 a0 = *(const float4*)(Abase + (size_t)r * DIM + k0 + c8);
    float4 a1 = *(const float4*)(Abase + (size_t)r * DIM + k0 + c8 + 4);
    float4 a2 = *(const float4*)(Abase + (size_t)(r + 64) * DIM + k0 + c8);
    float4 a3 = *(const float4*)(Abase + (size_t)(r + 64) * DIM + k0 + c8 + 4);
    float4 b0 = *(const float4*)(Bbase + (size_t)r * DIM + k0 + c8);
    float4 b1 = *(const float4*)(Bbase + (size_t)r * DIM + k0 + c8 + 4);
    float4 b2 = *(const float4*)(Bbase + (size_t)(r + 64) * DIM + k0 + c8);
    float4 b3 = *(const float4*)(Bbase + (size_t)(r + 64) * DIM + k0 + c8 + 4);
    __syncthreads();
    *(f16x8*)&sA[r * LDSS + c8] = cvt8(a0, a1);
    *(f16x8*)&sA[(r + 64) * LDSS + c8] = cvt8(a2, a3);
    *(f16x8*)&sB[r * LDSS + c8] = cvt8(b0, b1);
    *(f16x8*)&sB[(r + 64) * LDSS + c8] = cvt8(b2, b3);
    __syncthreads();
    f16x8 aF[4], bF[4];
#pragma unroll
    for (int i = 0; i < 4; i++)
      aF[i] = *(const f16x8*)&sA[(wm * 64 + i * 16 + tm) * LDSS + quad * 8];
#pragma unroll
    for (int j = 0; j < 4; j++)
      bF[j] = *(const f16x8*)&sB[(wn * 64 + j * 16 + tm) * LDSS + quad * 8];
#pragma unroll
    for (int i = 0; i < 4; i++)
#pragma unroll
      for (int j = 0; j < 4; j++)
        acc[i][j] = __builtin_amdgcn_mfma_f32_16x16x32_f16(aF[i], bF[j], acc[i][j], 0, 0, 0);
  }
#pragma unroll
  for (int i = 0; i < 4; i++) {
#pragma unroll
    for (int rr = 0; rr < 4; rr++) {
      size_t rowoff = ((size_t)b * TQ + mt * BM + wm * 64 + i * 16 + quad * 4 + rr) * (size_t)TK;
#pragma unroll
      for (int j = 0; j < 4; j++)
        S[rowoff + nt * BN + wn * 64 + j * 16 + tm] = acc[i][j][rr];
    }
  }
}

__global__ __launch_bounds__(256) void ctx_kernel_fb(
    const float* __restrict__ W, const float* __restrict__ enc,
    float* __restrict__ C) {
  __shared__ _Float16 sA[BM * LDSS];
  __shared__ _Float16 sB[BN * LDSS];
  const int nt = blockIdx.x;
  const int mt = blockIdx.y;
  const int b = blockIdx.z;
  const int t = threadIdx.x;
  const int lane = t & 63, wave = t >> 6;
  const int wm = wave >> 1, wn = wave & 1;
  const int tm = lane & 15, quad = lane >> 4;
  const float* Abase = W + ((size_t)b * TQ + mt * BM) * TK;
  const float* Ebase = enc + (size_t)b * TK * DIM + nt * BN;
  f32x4 acc[4][4] = {};
  const int r = t >> 2;
  const int c8 = (t & 3) * 8;
  const int kkB = (t & 7) * 4;
  const int nnB = (t >> 3) * 4;
  for (int k0 = 0; k0 < TK; k0 += BK) {
    float4 a0 = *(const float4*)(Abase + (size_t)r * TK + k0 + c8);
    float4 a1 = *(const float4*)(Abase + (size_t)r * TK + k0 + c8 + 4);
    float4 a2 = *(const float4*)(Abase + (size_t)(r + 64) * TK + k0 + c8);
    float4 a3 = *(const float4*)(Abase + (size_t)(r + 64) * TK + k0 + c8 + 4);
    float4 f[4];
#pragma unroll
    for (int i = 0; i < 4; i++)
      f[i] = *(const float4*)(Ebase + (size_t)(k0 + kkB + i) * DIM + nnB);
    __syncthreads();
    *(f16x8*)&sA[r * LDSS + c8] = cvt8(a0, a1);
    *(f16x8*)&sA[(r + 64) * LDSS + c8] = cvt8(a2, a3);
#pragma unroll
    for (int c = 0; c < 4; c++) {
      f16x4 h;
      h[0] = (_Float16)((&f[0].x)[c]);
      h[1] = (_Float16)((&f[1].x)[c]);
      h[2] = (_Float16)((&f[2].x)[c]);
      h[3] = (_Float16)((&f[3].x)[c]);
      *(f16x4*)&sB[(nnB + c) * LDSS + kkB] = h;
    }
    __syncthreads();
    f16x8 aF[4], bF[4];
#pragma unroll
    for (int i = 0; i < 4; i++)
      aF[i] = *(const f16x8*)&sA[(wm * 64 + i * 16 + tm) * LDSS + quad * 8];
#pragma unroll
    for (int j = 0; j < 4; j++)
      bF[j] = *(const f16x8*)&sB[(wn * 64 + j * 16 + tm) * LDSS + quad * 8];
#pragma unroll
    for (int i = 0; i < 4; i++)
#pragma unroll
      for (int j = 0; j < 4; j++)
        acc[i][j] = __builtin_amdgcn_mfma_f32_16x16x32_f16(aF[i], bF[j], acc[i][j], 0, 0, 0);
  }
#pragma unroll
  for (int i = 0; i < 4; i++) {
#pragma unroll
    for (int rr = 0; rr < 4; rr++) {
      size_t rowoff = ((size_t)b * TQ + mt * BM + wm * 64 + i * 16 + quad * 4 + rr) * (size_t)DIM;
#pragma unroll
      for (int j = 0; j < 4; j++)
        C[rowoff + nt * BN + wn * 64 + j * 16 + tm] = acc[i][j][rr];
    }
  }
}

// ===========================================================================
extern "C" void kernel_launch(void* const* d_in, const int* in_sizes, int n_in,
                              void* d_out, int out_size, void* d_ws, size_t ws_size,
                              hipStream_t stream) {
  const float* dec = (const float*)d_in[0];
  const float* enc = (const float*)d_in[1];
  const int* mask = (const int*)d_in[2];

  float* ctx = (float*)d_out;               // [8, 2048, 1024]
  float* attn = (float*)d_out + CTX_ELEMS;  // [8, 2048, 2048]

  dim3 block(256);

  if (ws_size >= WS_NEEDED_BYTES) {
    _Float16* dec16 = (_Float16*)d_ws + WS_DEC;
    _Float16* enc16 = (_Float16*)d_ws + WS_ENC;
    _Float16* encT = (_Float16*)d_ws + WS_ENCT;
    _Float16* W16 = (_Float16*)d_ws + WS_W;

    convert_kernel<<<dim3(CTX_ELEMS / (256 * 8), 2), block, 0, stream>>>(dec, enc, dec16, enc16);
    transpose_kernel<<<dim3(TK / 64, DIM / 64, BATCH), block, 0, stream>>>(enc, encT);
    gemm_nt<TQ, TK, DIM><<<dim3(TK / 128, TQ / 128, BATCH), block, 0, stream>>>(dec16, enc16, attn);
    softmax_kernel<<<dim3(BATCH * TQ), block, 0, stream>>>(attn, mask, W16);
    gemm_nt<TQ, DIM, TK><<<dim3(DIM / 128, TQ / 128, BATCH), block, 0, stream>>>(W16, encT, ctx);
  } else {
    score_kernel_fb<<<dim3(TK / BN, TQ / BM, BATCH), block, 0, stream>>>(dec, enc, attn);
    softmax_kernel<<<dim3(BATCH * TQ), block, 0, stream>>>(attn, mask, nullptr);
    ctx_kernel_fb<<<dim3(DIM / BN, TQ / BM, BATCH), block, 0, stream>>>(attn, enc, ctx);
  }
}

// Round 3
// 581.689 us; speedup vs baseline: 1.0398x; 1.0211x over previous
//
#include <hip/hip_runtime.h>
#include <cstddef>
#include <cstdint>

typedef _Float16 f16x8 __attribute__((ext_vector_type(8)));
typedef _Float16 f16x4 __attribute__((ext_vector_type(4)));
typedef float f32x4 __attribute__((ext_vector_type(4)));

static constexpr int BATCH = 8;
static constexpr int TQ = 2048;
static constexpr int TK = 2048;
static constexpr int DIM = 1024;
static constexpr size_t CTX_ELEMS = (size_t)BATCH * TQ * DIM;   // 16,777,216
static constexpr size_t ATT_ELEMS = (size_t)BATCH * TQ * TK;    // 33,554,432

// ws layout (halves): dec16 | enc16 | encT16 | W16
static constexpr size_t WS_DEC = 0;
static constexpr size_t WS_ENC = WS_DEC + CTX_ELEMS;
static constexpr size_t WS_ENCT = WS_ENC + CTX_ELEMS;
static constexpr size_t WS_W = WS_ENCT + CTX_ELEMS;
static constexpr size_t WS_NEEDED_BYTES = (WS_W + ATT_ELEMS) * 2;  // 167.8 MB

__device__ __forceinline__ void async16(const void* g, const void* l) {
  __builtin_amdgcn_global_load_lds(
      (const __attribute__((address_space(1))) unsigned int*)g,
      (__attribute__((address_space(3))) unsigned int*)l, 16, 0, 0);
}

__device__ __forceinline__ f16x8 cvt8(float4 a, float4 b) {
  f16x8 h;
  h[0] = (_Float16)a.x; h[1] = (_Float16)a.y; h[2] = (_Float16)a.z; h[3] = (_Float16)a.w;
  h[4] = (_Float16)b.x; h[5] = (_Float16)b.y; h[6] = (_Float16)b.z; h[7] = (_Float16)b.w;
  return h;
}

// ===========================================================================
// FAST PATH (needs 168 MB ws)
// ===========================================================================

// dec fp32 -> fp16 elementwise.
__global__ __launch_bounds__(256) void convert_dec_kernel(
    const float* __restrict__ dec, _Float16* __restrict__ dec16) {
  size_t i = ((size_t)blockIdx.x * 256 + threadIdx.x) * 8;
  float4 a = *(const float4*)(dec + i);
  float4 b = *(const float4*)(dec + i + 4);
  *(f16x8*)(dec16 + i) = cvt8(a, b);
}

// enc fp32 [b][k][d] -> enc16 fp16 [b][k][d] AND encT16 fp16 [b][d][k].
// Reads enc exactly once (64x64 tiles via LDS for the transpose).
__global__ __launch_bounds__(256) void convert_enc_kernel(
    const float* __restrict__ enc, _Float16* __restrict__ enc16,
    _Float16* __restrict__ encT) {
  __shared__ _Float16 sT[64 * 72];
  const int k0 = blockIdx.x * 64, d0 = blockIdx.y * 64, b = blockIdx.z;
  const int t = threadIdx.x;
  const int krow = t >> 2;           // 0..63
  const int dcol = (t & 3) * 16;     // 0,16,32,48

  const float* src = enc + ((size_t)b * TK + k0 + krow) * DIM + d0 + dcol;
  float4 f0 = *(const float4*)(src);
  float4 f1 = *(const float4*)(src + 4);
  float4 f2 = *(const float4*)(src + 8);
  float4 f3 = *(const float4*)(src + 12);
  _Float16 h[16];
#pragma unroll
  for (int i = 0; i < 4; i++) {
    h[i]      = (_Float16)((&f0.x)[i]);
    h[i + 4]  = (_Float16)((&f1.x)[i]);
    h[i + 8]  = (_Float16)((&f2.x)[i]);
    h[i + 12] = (_Float16)((&f3.x)[i]);
  }
  // straight fp16 copy
  _Float16* dsts = enc16 + ((size_t)b * TK + k0 + krow) * DIM + d0 + dcol;
  *(f16x8*)dsts = *(const f16x8*)&h[0];
  *(f16x8*)(dsts + 8) = *(const f16x8*)&h[8];
  // transposed via LDS
#pragma unroll
  for (int i = 0; i < 16; i++)
    sT[(dcol + i) * 72 + krow] = h[i];
  __syncthreads();

  const int drow = t >> 2;
  const int kg = (t & 3) * 16;
  f16x8 v0 = *(const f16x8*)&sT[drow * 72 + kg];
  f16x8 v1 = *(const f16x8*)&sT[drow * 72 + kg + 8];
  _Float16* dst = encT + ((size_t)b * DIM + d0 + drow) * TK + k0 + kg;
  *(f16x8*)dst = v0;
  *(f16x8*)(dst + 8) = v1;
}

// NT GEMM, BK=64: A[b][M][K], B[b][N][K] fp16 k-contiguous; C[b][M][N] fp32.
// Two 32-half sub-tiles per barrier pair -> half the vmcnt(0) drains of BK=32.
template <int M, int N, int K>
__global__ __launch_bounds__(256, 4) void gemm_nt(
    const _Float16* __restrict__ A, const _Float16* __restrict__ B,
    float* __restrict__ C) {
  __shared__ _Float16 sA[2][128 * 32];
  __shared__ _Float16 sB[2][128 * 32];

  const int nt = blockIdx.x, mt = blockIdx.y, b = blockIdx.z;
  const int t = threadIdx.x;
  const int lane = t & 63, w = t >> 6;
  const int wm = w >> 1, wn = w & 1;
  const int tm = lane & 15, quad = lane >> 4;

  const _Float16* Ab = A + ((size_t)b * M + mt * 128) * K;
  const _Float16* Bb = B + ((size_t)b * N + nt * 128) * K;

  const int srow = lane >> 2;        // 0..15
  const int scol = (lane & 3) * 8;   // 0,8,16,24 halves

  f32x4 acc[4][4] = {};

  for (int k0 = 0; k0 < K; k0 += 64) {
    __syncthreads();  // previous iteration's LDS reads done
#pragma unroll
    for (int s = 0; s < 2; s++) {
      async16(Ab + (size_t)(w * 32 + srow) * K + k0 + s * 32 + scol, &sA[s][(w * 32) * 32]);
      async16(Ab + (size_t)(w * 32 + 16 + srow) * K + k0 + s * 32 + scol, &sA[s][(w * 32 + 16) * 32]);
      async16(Bb + (size_t)(w * 32 + srow) * K + k0 + s * 32 + scol, &sB[s][(w * 32) * 32]);
      async16(Bb + (size_t)(w * 32 + 16 + srow) * K + k0 + s * 32 + scol, &sB[s][(w * 32 + 16) * 32]);
    }
    __syncthreads();  // staging drained (vmcnt) + all waves arrived

#pragma unroll
    for (int s = 0; s < 2; s++) {
      f16x8 aF[4], bF[4];
#pragma unroll
      for (int i = 0; i < 4; i++)
        aF[i] = *(const f16x8*)&sA[s][(wm * 64 + i * 16 + tm) * 32 + quad * 8];
#pragma unroll
      for (int j = 0; j < 4; j++)
        bF[j] = *(const f16x8*)&sB[s][(wn * 64 + j * 16 + tm) * 32 + quad * 8];

#pragma unroll
      for (int i = 0; i < 4; i++)
#pragma unroll
        for (int j = 0; j < 4; j++)
          acc[i][j] = __builtin_amdgcn_mfma_f32_16x16x32_f16(aF[i], bF[j], acc[i][j], 0, 0, 0);
    }
  }

  // C/D layout: col = lane&15, row = quad*4 + reg
#pragma unroll
  for (int i = 0; i < 4; i++) {
#pragma unroll
    for (int rr = 0; rr < 4; rr++) {
      size_t rowoff = ((size_t)b * M + mt * 128 + wm * 64 + i * 16 + quad * 4 + rr) * (size_t)N;
#pragma unroll
      for (int j = 0; j < 4; j++)
        C[rowoff + nt * 128 + wn * 64 + j * 16 + tm] = acc[i][j][rr];
    }
  }
}

// masked softmax in-place over S rows; optionally also emits fp16 copy.
__global__ __launch_bounds__(256) void softmax_kernel(
    float* __restrict__ S, const int* __restrict__ mask, _Float16* __restrict__ W16) {
  const int row = blockIdx.x;
  const int b = row >> 11;
  float* srow = S + (size_t)row * TK;
  const int* mrow = mask + (size_t)b * TK;
  const int t = threadIdx.x;

  float4 s0 = *(const float4*)(srow + t * 8);
  float4 s1 = *(const float4*)(srow + t * 8 + 4);
  int4 m0 = *(const int4*)(mrow + t * 8);
  int4 m1 = *(const int4*)(mrow + t * 8 + 4);

  float v[8] = {s0.x, s0.y, s0.z, s0.w, s1.x, s1.y, s1.z, s1.w};
  const int mm[8] = {m0.x, m0.y, m0.z, m0.w, m1.x, m1.y, m1.z, m1.w};
#pragma unroll
  for (int i = 0; i < 8; i++)
    if (!mm[i]) v[i] += -1e9f;

  float mx = v[0];
#pragma unroll
  for (int i = 1; i < 8; i++) mx = fmaxf(mx, v[i]);
#pragma unroll
  for (int off = 32; off > 0; off >>= 1) mx = fmaxf(mx, __shfl_down(mx, off));

  __shared__ float redm[4];
  __shared__ float reds[4];
  if ((t & 63) == 0) redm[t >> 6] = mx;
  __syncthreads();
  mx = fmaxf(fmaxf(redm[0], redm[1]), fmaxf(redm[2], redm[3]));

  float e[8];
  float lsum = 0.f;
#pragma unroll
  for (int i = 0; i < 8; i++) {
    e[i] = __expf(v[i] - mx);
    lsum += e[i];
  }
#pragma unroll
  for (int off = 32; off > 0; off >>= 1) lsum += __shfl_down(lsum, off);
  if ((t & 63) == 0) reds[t >> 6] = lsum;
  __syncthreads();
  const float inv = 1.0f / (reds[0] + reds[1] + reds[2] + reds[3]);

  float4 o0 = {e[0] * inv, e[1] * inv, e[2] * inv, e[3] * inv};
  float4 o1 = {e[4] * inv, e[5] * inv, e[6] * inv, e[7] * inv};
  *(float4*)(srow + t * 8) = o0;
  *(float4*)(srow + t * 8 + 4) = o1;
  if (W16) {
    f16x8 h;
    h[0] = (_Float16)o0.x; h[1] = (_Float16)o0.y; h[2] = (_Float16)o0.z; h[3] = (_Float16)o0.w;
    h[4] = (_Float16)o1.x; h[5] = (_Float16)o1.y; h[6] = (_Float16)o1.z; h[7] = (_Float16)o1.w;
    *(f16x8*)(W16 + (size_t)row * TK + t * 8) = h;
  }
}

// ===========================================================================
// FALLBACK PATH (round-1 kernels, used only if ws too small)
// ===========================================================================
static constexpr int BM = 128, BN = 128, BK = 32;
static constexpr int LDSS = 40;

__global__ __launch_bounds__(256) void score_kernel_fb(
    const float* __restrict__ dec, const float* __restrict__ enc,
    float* __restrict__ S) {
  __shared__ _Float16 sA[BM * LDSS];
  __shared__ _Float16 sB[BN * LDSS];
  const int nt = blockIdx.x, mt = blockIdx.y, b = blockIdx.z;
  const int t = threadIdx.x;
  const int lane = t & 63, wave = t >> 6;
  const int wm = wave >> 1, wn = wave & 1;
  const int tm = lane & 15, quad = lane >> 4;
  const float* Abase = dec + ((size_t)b * TQ + mt * BM) * DIM;
  const float* Bbase = enc + ((size_t)b * TK + nt * BN) * DIM;
  f32x4 acc[4][4] = {};
  const int r = t >> 2;
  const int c8 = (t & 3) * 8;
  for (int k0 = 0; k0 < DIM; k0 += BK) {
    float4 a0 = *(const float4*)(Abase + (size_t)r * DIM + k0 + c8);
    float4 a1 = *(const float4*)(Abase + (size_t)r * DIM + k0 + c8 + 4);
    float4 a2 = *(const float4*)(Abase + (size_t)(r + 64) * DIM + k0 + c8);
    float4 a3 = *(const float4*)(Abase + (size_t)(r + 64) * DIM + k0 + c8 + 4);
    float4 b0 = *(const float4*)(Bbase + (size_t)r * DIM + k0 + c8);
    float4 b1 = *(const float4*)(Bbase + (size_t)r * DIM + k0 + c8 + 4);
    float4 b2 = *(const float4*)(Bbase + (size_t)(r + 64) * DIM + k0 + c8);
    float4 b3 = *(const float4*)(Bbase + (size_t)(r + 64) * DIM + k0 + c8 + 4);
    __syncthreads();
    *(f16x8*)&sA[r * LDSS + c8] = cvt8(a0, a1);
    *(f16x8*)&sA[(r + 64) * LDSS + c8] = cvt8(a2, a3);
    *(f16x8*)&sB[r * LDSS + c8] = cvt8(b0, b1);
    *(f16x8*)&sB[(r + 64) * LDSS + c8] = cvt8(b2, b3);
    __syncthreads();
    f16x8 aF[4], bF[4];
#pragma unroll
    for (int i = 0; i < 4; i++)
      aF[i] = *(const f16x8*)&sA[(wm * 64 + i * 16 + tm) * LDSS + quad * 8];
#pragma unroll
    for (int j = 0; j < 4; j++)
      bF[j] = *(const f16x8*)&sB[(wn * 64 + j * 16 + tm) * LDSS + quad * 8];
#pragma unroll
    for (int i = 0; i < 4; i++)
#pragma unroll
      for (int j = 0; j < 4; j++)
        acc[i][j] = __builtin_amdgcn_mfma_f32_16x16x32_f16(aF[i], bF[j], acc[i][j], 0, 0, 0);
  }
#pragma unroll
  for (int i = 0; i < 4; i++) {
#pragma unroll
    for (int rr = 0; rr < 4; rr++) {
      size_t rowoff = ((size_t)b * TQ + mt * BM + wm * 64 + i * 16 + quad * 4 + rr) * (size_t)TK;
#pragma unroll
      for (int j = 0; j < 4; j++)
        S[rowoff + nt * BN + wn * 64 + j * 16 + tm] = acc[i][j][rr];
    }
  }
}

__global__ __launch_bounds__(256) void ctx_kernel_fb(
    const float* __restrict__ W, const float* __restrict__ enc,
    float* __restrict__ C) {
  __shared__ _Float16 sA[BM * LDSS];
  __shared__ _Float16 sB[BN * LDSS];
  const int nt = blockIdx.x;
  const int mt = blockIdx.y;
  const int b = blockIdx.z;
  const int t = threadIdx.x;
  const int lane = t & 63, wave = t >> 6;
  const int wm = wave >> 1, wn = wave & 1;
  const int tm = lane & 15, quad = lane >> 4;
  const float* Abase = W + ((size_t)b * TQ + mt * BM) * TK;
  const float* Ebase = enc + (size_t)b * TK * DIM + nt * BN;
  f32x4 acc[4][4] = {};
  const int r = t >> 2;
  const int c8 = (t & 3) * 8;
  const int kkB = (t & 7) * 4;
  const int nnB = (t >> 3) * 4;
  for (int k0 = 0; k0 < TK; k0 += BK) {
    float4 a0 = *(const float4*)(Abase + (size_t)r * TK + k0 + c8);
    float4 a1 = *(const float4*)(Abase + (size_t)r * TK + k0 + c8 + 4);
    float4 a2 = *(const float4*)(Abase + (size_t)(r + 64) * TK + k0 + c8);
    float4 a3 = *(const float4*)(Abase + (size_t)(r + 64) * TK + k0 + c8 + 4);
    float4 f[4];
#pragma unroll
    for (int i = 0; i < 4; i++)
      f[i] = *(const float4*)(Ebase + (size_t)(k0 + kkB + i) * DIM + nnB);
    __syncthreads();
    *(f16x8*)&sA[r * LDSS + c8] = cvt8(a0, a1);
    *(f16x8*)&sA[(r + 64) * LDSS + c8] = cvt8(a2, a3);
#pragma unroll
    for (int c = 0; c < 4; c++) {
      f16x4 h;
      h[0] = (_Float16)((&f[0].x)[c]);
      h[1] = (_Float16)((&f[1].x)[c]);
      h[2] = (_Float16)((&f[2].x)[c]);
      h[3] = (_Float16)((&f[3].x)[c]);
      *(f16x4*)&sB[(nnB + c) * LDSS + kkB] = h;
    }
    __syncthreads();
    f16x8 aF[4], bF[4];
#pragma unroll
    for (int i = 0; i < 4; i++)
      aF[i] = *(const f16x8*)&sA[(wm * 64 + i * 16 + tm) * LDSS + quad * 8];
#pragma unroll
    for (int j = 0; j < 4; j++)
      bF[j] = *(const f16x8*)&sB[(wn * 64 + j * 16 + tm) * LDSS + quad * 8];
#pragma unroll
    for (int i = 0; i < 4; i++)
#pragma unroll
      for (int j = 0; j < 4; j++)
        acc[i][j] = __builtin_amdgcn_mfma_f32_16x16x32_f16(aF[i], bF[j], acc[i][j], 0, 0, 0);
  }
#pragma unroll
  for (int i = 0; i < 4; i++) {
#pragma unroll
    for (int rr = 0; rr < 4; rr++) {
      size_t rowoff = ((size_t)b * TQ + mt * BM + wm * 64 + i * 16 + quad * 4 + rr) * (size_t)DIM;
#pragma unroll
      for (int j = 0; j < 4; j++)
        C[rowoff + nt * BN + wn * 64 + j * 16 + tm] = acc[i][j][rr];
    }
  }
}

// ===========================================================================
extern "C" void kernel_launch(void* const* d_in, const int* in_sizes, int n_in,
                              void* d_out, int out_size, void* d_ws, size_t ws_size,
                              hipStream_t stream) {
  const float* dec = (const float*)d_in[0];
  const float* enc = (const float*)d_in[1];
  const int* mask = (const int*)d_in[2];

  float* ctx = (float*)d_out;               // [8, 2048, 1024]
  float* attn = (float*)d_out + CTX_ELEMS;  // [8, 2048, 2048]

  dim3 block(256);

  if (ws_size >= WS_NEEDED_BYTES) {
    _Float16* dec16 = (_Float16*)d_ws + WS_DEC;
    _Float16* enc16 = (_Float16*)d_ws + WS_ENC;
    _Float16* encT = (_Float16*)d_ws + WS_ENCT;
    _Float16* W16 = (_Float16*)d_ws + WS_W;

    convert_dec_kernel<<<dim3(CTX_ELEMS / (256 * 8)), block, 0, stream>>>(dec, dec16);
    convert_enc_kernel<<<dim3(TK / 64, DIM / 64, BATCH), block, 0, stream>>>(enc, enc16, encT);
    gemm_nt<TQ, TK, DIM><<<dim3(TK / 128, TQ / 128, BATCH), block, 0, stream>>>(dec16, enc16, attn);
    softmax_kernel<<<dim3(BATCH * TQ), block, 0, stream>>>(attn, mask, W16);
    gemm_nt<TQ, DIM, TK><<<dim3(DIM / 128, TQ / 128, BATCH), block, 0, stream>>>(W16, encT, ctx);
  } else {
    score_kernel_fb<<<dim3(TK / BN, TQ / BM, BATCH), block, 0, stream>>>(dec, enc, attn);
    softmax_kernel<<<dim3(BATCH * TQ), block, 0, stream>>>(attn, mask, nullptr);
    ctx_kernel_fb<<<dim3(DIM / BN, TQ / BM, BATCH), block, 0, stream>>>(attn, enc, ctx);
  }
}

// Round 4
// 508.799 us; speedup vs baseline: 1.1888x; 1.1433x over previous
//
#include <hip/hip_runtime.h>
#include <cstddef>
#include <cstdint>

typedef _Float16 f16x8 __attribute__((ext_vector_type(8)));
typedef _Float16 f16x4 __attribute__((ext_vector_type(4)));
typedef float f32x4 __attribute__((ext_vector_type(4)));

static constexpr int BATCH = 8;
static constexpr int TQ = 2048;
static constexpr int TK = 2048;
static constexpr int DIM = 1024;
static constexpr size_t CTX_ELEMS = (size_t)BATCH * TQ * DIM;   // 16,777,216
static constexpr size_t ATT_ELEMS = (size_t)BATCH * TQ * TK;    // 33,554,432

// ws layout (halves): dec16 | enc16 | encT16 | W16
static constexpr size_t WS_DEC = 0;
static constexpr size_t WS_ENC = WS_DEC + CTX_ELEMS;
static constexpr size_t WS_ENCT = WS_ENC + CTX_ELEMS;
static constexpr size_t WS_W = WS_ENCT + CTX_ELEMS;
static constexpr size_t WS_NEEDED_BYTES = (WS_W + ATT_ELEMS) * 2;  // 167.8 MB

__device__ __forceinline__ void async16(const void* g, const void* l) {
  __builtin_amdgcn_global_load_lds(
      (const __attribute__((address_space(1))) unsigned int*)g,
      (__attribute__((address_space(3))) unsigned int*)l, 16, 0, 0);
}

__device__ __forceinline__ f16x8 cvt8(float4 a, float4 b) {
  f16x8 h;
  h[0] = (_Float16)a.x; h[1] = (_Float16)a.y; h[2] = (_Float16)a.z; h[3] = (_Float16)a.w;
  h[4] = (_Float16)b.x; h[5] = (_Float16)b.y; h[6] = (_Float16)b.z; h[7] = (_Float16)b.w;
  return h;
}

// ===========================================================================
// FAST PATH (needs 168 MB ws)
// ===========================================================================

// dec fp32 -> fp16 elementwise.
__global__ __launch_bounds__(256) void convert_dec_kernel(
    const float* __restrict__ dec, _Float16* __restrict__ dec16) {
  size_t i = ((size_t)blockIdx.x * 256 + threadIdx.x) * 8;
  float4 a = *(const float4*)(dec + i);
  float4 b = *(const float4*)(dec + i + 4);
  *(f16x8*)(dec16 + i) = cvt8(a, b);
}

// enc fp32 [b][k][d] -> enc16 fp16 [b][k][d] AND encT16 fp16 [b][d][k].
__global__ __launch_bounds__(256) void convert_enc_kernel(
    const float* __restrict__ enc, _Float16* __restrict__ enc16,
    _Float16* __restrict__ encT) {
  __shared__ _Float16 sT[64 * 72];
  const int k0 = blockIdx.x * 64, d0 = blockIdx.y * 64, b = blockIdx.z;
  const int t = threadIdx.x;
  const int krow = t >> 2;           // 0..63
  const int dcol = (t & 3) * 16;     // 0,16,32,48

  const float* src = enc + ((size_t)b * TK + k0 + krow) * DIM + d0 + dcol;
  float4 f0 = *(const float4*)(src);
  float4 f1 = *(const float4*)(src + 4);
  float4 f2 = *(const float4*)(src + 8);
  float4 f3 = *(const float4*)(src + 12);
  _Float16 h[16];
#pragma unroll
  for (int i = 0; i < 4; i++) {
    h[i]      = (_Float16)((&f0.x)[i]);
    h[i + 4]  = (_Float16)((&f1.x)[i]);
    h[i + 8]  = (_Float16)((&f2.x)[i]);
    h[i + 12] = (_Float16)((&f3.x)[i]);
  }
  _Float16* dsts = enc16 + ((size_t)b * TK + k0 + krow) * DIM + d0 + dcol;
  *(f16x8*)dsts = *(const f16x8*)&h[0];
  *(f16x8*)(dsts + 8) = *(const f16x8*)&h[8];
#pragma unroll
  for (int i = 0; i < 16; i++)
    sT[(dcol + i) * 72 + krow] = h[i];
  __syncthreads();

  const int drow = t >> 2;
  const int kg = (t & 3) * 16;
  f16x8 v0 = *(const f16x8*)&sT[drow * 72 + kg];
  f16x8 v1 = *(const f16x8*)&sT[drow * 72 + kg + 8];
  _Float16* dst = encT + ((size_t)b * DIM + d0 + drow) * TK + k0 + kg;
  *(f16x8*)dst = v0;
  *(f16x8*)(dst + 8) = v1;
}

// NT GEMM, 256x128 macro-tile, BK=64 (two 32-half sub-tiles).
// Grid: (b, nt, mt) with b FASTEST -> all blocks of a batch share one XCD,
// so A-sharing (across nt) and B-sharing (across mt) dedupe in that L2.
// 4 waves; wave w computes rows [w*64, w*64+64) x all 128 cols.
template <int M, int N, int K>
__global__ __launch_bounds__(256, 2) void gemm_nt(
    const _Float16* __restrict__ A, const _Float16* __restrict__ B,
    float* __restrict__ C) {
  __shared__ _Float16 sA[2][256 * 32];
  __shared__ _Float16 sB[2][128 * 32];

  const int b = blockIdx.x, nt = blockIdx.y, mt = blockIdx.z;
  const int t = threadIdx.x;
  const int lane = t & 63, w = t >> 6;
  const int tm = lane & 15, quad = lane >> 4;

  const _Float16* Ab = A + ((size_t)b * M + mt * 256) * K;
  const _Float16* Bb = B + ((size_t)b * N + nt * 128) * K;

  const int srow = lane >> 2;        // 0..15
  const int scol = (lane & 3) * 8;   // 0,8,16,24 halves

  f32x4 acc[4][8] = {};

  for (int k0 = 0; k0 < K; k0 += 64) {
    __syncthreads();  // previous iteration's LDS reads done
#pragma unroll
    for (int s = 0; s < 2; s++) {
      // wave w stages sA rows [w*64, w*64+64) and sB rows [w*32, w*32+32)
#pragma unroll
      for (int i = 0; i < 4; i++)
        async16(Ab + (size_t)(w * 64 + 16 * i + srow) * K + k0 + s * 32 + scol,
                &sA[s][(w * 64 + 16 * i) * 32]);
#pragma unroll
      for (int i = 0; i < 2; i++)
        async16(Bb + (size_t)(w * 32 + 16 * i + srow) * K + k0 + s * 32 + scol,
                &sB[s][(w * 32 + 16 * i) * 32]);
    }
    __syncthreads();  // staging drained + all waves arrived

#pragma unroll
    for (int s = 0; s < 2; s++) {
      f16x8 aF[4], bF[8];
#pragma unroll
      for (int i = 0; i < 4; i++)
        aF[i] = *(const f16x8*)&sA[s][(w * 64 + i * 16 + tm) * 32 + quad * 8];
#pragma unroll
      for (int j = 0; j < 8; j++)
        bF[j] = *(const f16x8*)&sB[s][(j * 16 + tm) * 32 + quad * 8];

#pragma unroll
      for (int i = 0; i < 4; i++)
#pragma unroll
        for (int j = 0; j < 8; j++)
          acc[i][j] = __builtin_amdgcn_mfma_f32_16x16x32_f16(aF[i], bF[j], acc[i][j], 0, 0, 0);
    }
  }

  // C/D layout: col = lane&15, row = quad*4 + reg
#pragma unroll
  for (int i = 0; i < 4; i++) {
#pragma unroll
    for (int rr = 0; rr < 4; rr++) {
      size_t rowoff = ((size_t)b * M + mt * 256 + w * 64 + i * 16 + quad * 4 + rr) * (size_t)N;
#pragma unroll
      for (int j = 0; j < 8; j++)
        C[rowoff + nt * 128 + j * 16 + tm] = acc[i][j][rr];
    }
  }
}

// masked softmax in-place over S rows; optionally also emits fp16 copy.
__global__ __launch_bounds__(256) void softmax_kernel(
    float* __restrict__ S, const int* __restrict__ mask, _Float16* __restrict__ W16) {
  const int row = blockIdx.x;
  const int b = row >> 11;
  float* srow = S + (size_t)row * TK;
  const int* mrow = mask + (size_t)b * TK;
  const int t = threadIdx.x;

  float4 s0 = *(const float4*)(srow + t * 8);
  float4 s1 = *(const float4*)(srow + t * 8 + 4);
  int4 m0 = *(const int4*)(mrow + t * 8);
  int4 m1 = *(const int4*)(mrow + t * 8 + 4);

  float v[8] = {s0.x, s0.y, s0.z, s0.w, s1.x, s1.y, s1.z, s1.w};
  const int mm[8] = {m0.x, m0.y, m0.z, m0.w, m1.x, m1.y, m1.z, m1.w};
#pragma unroll
  for (int i = 0; i < 8; i++)
    if (!mm[i]) v[i] += -1e9f;

  float mx = v[0];
#pragma unroll
  for (int i = 1; i < 8; i++) mx = fmaxf(mx, v[i]);
#pragma unroll
  for (int off = 32; off > 0; off >>= 1) mx = fmaxf(mx, __shfl_down(mx, off));

  __shared__ float redm[4];
  __shared__ float reds[4];
  if ((t & 63) == 0) redm[t >> 6] = mx;
  __syncthreads();
  mx = fmaxf(fmaxf(redm[0], redm[1]), fmaxf(redm[2], redm[3]));

  float e[8];
  float lsum = 0.f;
#pragma unroll
  for (int i = 0; i < 8; i++) {
    e[i] = __expf(v[i] - mx);
    lsum += e[i];
  }
#pragma unroll
  for (int off = 32; off > 0; off >>= 1) lsum += __shfl_down(lsum, off);
  if ((t & 63) == 0) reds[t >> 6] = lsum;
  __syncthreads();
  const float inv = 1.0f / (reds[0] + reds[1] + reds[2] + reds[3]);

  float4 o0 = {e[0] * inv, e[1] * inv, e[2] * inv, e[3] * inv};
  float4 o1 = {e[4] * inv, e[5] * inv, e[6] * inv, e[7] * inv};
  *(float4*)(srow + t * 8) = o0;
  *(float4*)(srow + t * 8 + 4) = o1;
  if (W16) {
    f16x8 h;
    h[0] = (_Float16)o0.x; h[1] = (_Float16)o0.y; h[2] = (_Float16)o0.z; h[3] = (_Float16)o0.w;
    h[4] = (_Float16)o1.x; h[5] = (_Float16)o1.y; h[6] = (_Float16)o1.z; h[7] = (_Float16)o1.w;
    *(f16x8*)(W16 + (size_t)row * TK + t * 8) = h;
  }
}

// ===========================================================================
// FALLBACK PATH (round-1 kernels, used only if ws too small)
// ===========================================================================
static constexpr int BM = 128, BN = 128, BK = 32;
static constexpr int LDSS = 40;

__global__ __launch_bounds__(256) void score_kernel_fb(
    const float* __restrict__ dec, const float* __restrict__ enc,
    float* __restrict__ S) {
  __shared__ _Float16 sA[BM * LDSS];
  __shared__ _Float16 sB[BN * LDSS];
  const int nt = blockIdx.x, mt = blockIdx.y, b = blockIdx.z;
  const int t = threadIdx.x;
  const int lane = t & 63, wave = t >> 6;
  const int wm = wave >> 1, wn = wave & 1;
  const int tm = lane & 15, quad = lane >> 4;
  const float* Abase = dec + ((size_t)b * TQ + mt * BM) * DIM;
  const float* Bbase = enc + ((size_t)b * TK + nt * BN) * DIM;
  f32x4 acc[4][4] = {};
  const int r = t >> 2;
  const int c8 = (t & 3) * 8;
  for (int k0 = 0; k0 < DIM; k0 += BK) {
    float4 a0 = *(const float4*)(Abase + (size_t)r * DIM + k0 + c8);
    float4 a1 = *(const float4*)(Abase + (size_t)r * DIM + k0 + c8 + 4);
    float4 a2 = *(const float4*)(Abase + (size_t)(r + 64) * DIM + k0 + c8);
    float4 a3 = *(const float4*)(Abase + (size_t)(r + 64) * DIM + k0 + c8 + 4);
    float4 b0 = *(const float4*)(Bbase + (size_t)r * DIM + k0 + c8);
    float4 b1 = *(const float4*)(Bbase + (size_t)r * DIM + k0 + c8 + 4);
    float4 b2 = *(const float4*)(Bbase + (size_t)(r + 64) * DIM + k0 + c8);
    float4 b3 = *(const float4*)(Bbase + (size_t)(r + 64) * DIM + k0 + c8 + 4);
    __syncthreads();
    *(f16x8*)&sA[r * LDSS + c8] = cvt8(a0, a1);
    *(f16x8*)&sA[(r + 64) * LDSS + c8] = cvt8(a2, a3);
    *(f16x8*)&sB[r * LDSS + c8] = cvt8(b0, b1);
    *(f16x8*)&sB[(r + 64) * LDSS + c8] = cvt8(b2, b3);
    __syncthreads();
    f16x8 aF[4], bF[4];
#pragma unroll
    for (int i = 0; i < 4; i++)
      aF[i] = *(const f16x8*)&sA[(wm * 64 + i * 16 + tm) * LDSS + quad * 8];
#pragma unroll
    for (int j = 0; j < 4; j++)
      bF[j] = *(const f16x8*)&sB[(wn * 64 + j * 16 + tm) * LDSS + quad * 8];
#pragma unroll
    for (int i = 0; i < 4; i++)
#pragma unroll
      for (int j = 0; j < 4; j++)
        acc[i][j] = __builtin_amdgcn_mfma_f32_16x16x32_f16(aF[i], bF[j], acc[i][j], 0, 0, 0);
  }
#pragma unroll
  for (int i = 0; i < 4; i++) {
#pragma unroll
    for (int rr = 0; rr < 4; rr++) {
      size_t rowoff = ((size_t)b * TQ + mt * BM + wm * 64 + i * 16 + quad * 4 + rr) * (size_t)TK;
#pragma unroll
      for (int j = 0; j < 4; j++)
        S[rowoff + nt * BN + wn * 64 + j * 16 + tm] = acc[i][j][rr];
    }
  }
}

__global__ __launch_bounds__(256) void ctx_kernel_fb(
    const float* __restrict__ W, const float* __restrict__ enc,
    float* __restrict__ C) {
  __shared__ _Float16 sA[BM * LDSS];
  __shared__ _Float16 sB[BN * LDSS];
  const int nt = blockIdx.x;
  const int mt = blockIdx.y;
  const int b = blockIdx.z;
  const int t = threadIdx.x;
  const int lane = t & 63, wave = t >> 6;
  const int wm = wave >> 1, wn = wave & 1;
  const int tm = lane & 15, quad = lane >> 4;
  const float* Abase = W + ((size_t)b * TQ + mt * BM) * TK;
  const float* Ebase = enc + (size_t)b * TK * DIM + nt * BN;
  f32x4 acc[4][4] = {};
  const int r = t >> 2;
  const int c8 = (t & 3) * 8;
  const int kkB = (t & 7) * 4;
  const int nnB = (t >> 3) * 4;
  for (int k0 = 0; k0 < TK; k0 += BK) {
    float4 a0 = *(const float4*)(Abase + (size_t)r * TK + k0 + c8);
    float4 a1 = *(const float4*)(Abase + (size_t)r * TK + k0 + c8 + 4);
    float4 a2 = *(const float4*)(Abase + (size_t)(r + 64) * TK + k0 + c8);
    float4 a3 = *(const float4*)(Abase + (size_t)(r + 64) * TK + k0 + c8 + 4);
    float4 f[4];
#pragma unroll
    for (int i = 0; i < 4; i++)
      f[i] = *(const float4*)(Ebase + (size_t)(k0 + kkB + i) * DIM + nnB);
    __syncthreads();
    *(f16x8*)&sA[r * LDSS + c8] = cvt8(a0, a1);
    *(f16x8*)&sA[(r + 64) * LDSS + c8] = cvt8(a2, a3);
#pragma unroll
    for (int c = 0; c < 4; c++) {
      f16x4 h;
      h[0] = (_Float16)((&f[0].x)[c]);
      h[1] = (_Float16)((&f[1].x)[c]);
      h[2] = (_Float16)((&f[2].x)[c]);
      h[3] = (_Float16)((&f[3].x)[c]);
      *(f16x4*)&sB[(nnB + c) * LDSS + kkB] = h;
    }
    __syncthreads();
    f16x8 aF[4], bF[4];
#pragma unroll
    for (int i = 0; i < 4; i++)
      aF[i] = *(const f16x8*)&sA[(wm * 64 + i * 16 + tm) * LDSS + quad * 8];
#pragma unroll
    for (int j = 0; j < 4; j++)
      bF[j] = *(const f16x8*)&sB[(wn * 64 + j * 16 + tm) * LDSS + quad * 8];
#pragma unroll
    for (int i = 0; i < 4; i++)
#pragma unroll
      for (int j = 0; j < 4; j++)
        acc[i][j] = __builtin_amdgcn_mfma_f32_16x16x32_f16(aF[i], bF[j], acc[i][j], 0, 0, 0);
  }
#pragma unroll
  for (int i = 0; i < 4; i++) {
#pragma unroll
    for (int rr = 0; rr < 4; rr++) {
      size_t rowoff = ((size_t)b * TQ + mt * BM + wm * 64 + i * 16 + quad * 4 + rr) * (size_t)DIM;
#pragma unroll
      for (int j = 0; j < 4; j++)
        C[rowoff + nt * BN + wn * 64 + j * 16 + tm] = acc[i][j][rr];
    }
  }
}

// ===========================================================================
extern "C" void kernel_launch(void* const* d_in, const int* in_sizes, int n_in,
                              void* d_out, int out_size, void* d_ws, size_t ws_size,
                              hipStream_t stream) {
  const float* dec = (const float*)d_in[0];
  const float* enc = (const float*)d_in[1];
  const int* mask = (const int*)d_in[2];

  float* ctx = (float*)d_out;               // [8, 2048, 1024]
  float* attn = (float*)d_out + CTX_ELEMS;  // [8, 2048, 2048]

  dim3 block(256);

  if (ws_size >= WS_NEEDED_BYTES) {
    _Float16* dec16 = (_Float16*)d_ws + WS_DEC;
    _Float16* enc16 = (_Float16*)d_ws + WS_ENC;
    _Float16* encT = (_Float16*)d_ws + WS_ENCT;
    _Float16* W16 = (_Float16*)d_ws + WS_W;

    convert_dec_kernel<<<dim3(CTX_ELEMS / (256 * 8)), block, 0, stream>>>(dec, dec16);
    convert_enc_kernel<<<dim3(TK / 64, DIM / 64, BATCH), block, 0, stream>>>(enc, enc16, encT);
    // grid: (b, nt, mt) — batch fastest for XCD-local L2 sharing
    gemm_nt<TQ, TK, DIM><<<dim3(BATCH, TK / 128, TQ / 256), block, 0, stream>>>(dec16, enc16, attn);
    softmax_kernel<<<dim3(BATCH * TQ), block, 0, stream>>>(attn, mask, W16);
    gemm_nt<TQ, DIM, TK><<<dim3(BATCH, DIM / 128, TQ / 256), block, 0, stream>>>(W16, encT, ctx);
  } else {
    score_kernel_fb<<<dim3(TK / BN, TQ / BM, BATCH), block, 0, stream>>>(dec, enc, attn);
    softmax_kernel<<<dim3(BATCH * TQ), block, 0, stream>>>(attn, mask, nullptr);
    ctx_kernel_fb<<<dim3(DIM / BN, TQ / BM, BATCH), block, 0, stream>>>(attn, enc, ctx);
  }
}